// Round 14
// baseline (253.799 us; speedup 1.0000x reference)
//
#include <hip/hip_runtime.h>
#include <hip/hip_bf16.h>

// Problem constants (B,N,C,NF) = (4,512,128,96)
#define NB 4
#define NN 512
#define CC 128

typedef __bf16 bf16x8 __attribute__((ext_vector_type(8)));
typedef __bf16 bf16x4 __attribute__((ext_vector_type(4)));
typedef float  f32x2  __attribute__((ext_vector_type(2)));
typedef float  f32x4  __attribute__((ext_vector_type(4)));
typedef int    i32x8  __attribute__((ext_vector_type(8)));

#define SCL 0x7F7F7F7F   // E8M0 127 (=1.0) in every byte — scale-neutral

// LDS-only barrier: drains lgkmcnt; global loads may stay in flight.
__device__ __forceinline__ void barrier_lds() {
    __builtin_amdgcn_s_waitcnt(0xC07F);
    __builtin_amdgcn_fence(__ATOMIC_RELEASE, "workgroup", "local");
    __builtin_amdgcn_s_barrier();
    __builtin_amdgcn_fence(__ATOMIC_ACQUIRE, "workgroup", "local");
}

__device__ __forceinline__ int pk4(float a, float b, float c, float d) {
    int p = __builtin_amdgcn_cvt_pk_fp8_f32(a, b, 0, false);
    return  __builtin_amdgcn_cvt_pk_fp8_f32(c, d, p, true);
}

// lrelu + pack 4 fp32 -> 4 fp8, using packed-f32 VALU (v_pk_mul/v_pk_max)
__device__ __forceinline__ int pk_lrelu(f32x4 a) {
    f32x2 lo = {a[0], a[1]}, hi = {a[2], a[3]};
    f32x2 llo = __builtin_elementwise_max(lo, lo * 0.01f);
    f32x2 lhi = __builtin_elementwise_max(hi, hi * 0.01f);
    int p = __builtin_amdgcn_cvt_pk_fp8_f32(llo[0], llo[1], 0, false);
    return  __builtin_amdgcn_cvt_pk_fp8_f32(lhi[0], lhi[1], p, true);
}

// load 32 fp8 (8 dwords) from LDS via 4x b64 — R12/R13 A/B showed b64 at
// stride ≡2 mod 32 dwords is conflict-free while b128 at stride ≡4 takes
// 4-way conflicts (SQ_LDS_BANK_CONFLICT 2.6e5 vs 1.36e7). Keep b64 + 136/200.
__device__ __forceinline__ i32x8 ld_lds32(const unsigned char* p) {
    i32x8 r;
    long long* q = (long long*)&r;
    q[0] = *(const long long*)(p);
    q[1] = *(const long long*)(p + 8);
    q[2] = *(const long long*)(p + 16);
    q[3] = *(const long long*)(p + 24);
    return r;
}

// ---------- prepass: x -> bf16; w1..w3 -> fp8; w4 -> fp8 zero-padded K=128 ----
__global__ void cvt_all(const float* __restrict__ x,  __bf16* __restrict__ xb,
                        const float* __restrict__ w1, int* __restrict__ w1f,
                        const float* __restrict__ w2, int* __restrict__ w2f,
                        const float* __restrict__ w3, int* __restrict__ w3f,
                        const float* __restrict__ w4, unsigned char* __restrict__ w4fp)
{
    int idx = blockIdx.x * blockDim.x + threadIdx.x;
    if (idx < 65536) {                       // x: 262144 f32 -> bf16
        float4 v = ((const float4*)x)[idx];
        bf16x4 o = { (__bf16)v.x, (__bf16)v.y, (__bf16)v.z, (__bf16)v.w };
        ((bf16x4*)xb)[idx] = o;
    } else if (idx < 85504) {                // w1..w3 -> fp8, packed rows
        const float* s; int* d; int off;
        if      (idx < 71680) { s = w1; d = w1f; off = idx - 65536; }  // 24576 f32
        else if (idx < 80896) { s = w2; d = w2f; off = idx - 71680; }  // 36864
        else                  { s = w3; d = w3f; off = idx - 80896; }  // 18432
        float4 v = ((const float4*)s)[off];
        d[off] = pk4(v.x, v.y, v.z, v.w);
    } else if (idx < 87808) {                // w4 -> fp8 into 128-wide rows
        int off = idx - 85504;               // 2304 float4s = 96 rows x 24
        int r = off / 24, c = (off % 24) * 4;
        float4 v = ((const float4*)w4)[off];
        *(int*)(w4fp + r * 128 + c) = pk4(v.x, v.y, v.z, v.w);
    } else if (idx < 88000) {                // zero-pad w4 rows, cols 96..127
        int p = idx - 87808;                 // 192 int4s
        int r = p >> 1;
        *(int4*)(w4fp + r * 128 + 96 + (p & 1) * 16) = make_int4(0, 0, 0, 0);
    }
}

// ---------------- fused edge-MLP kernel -------------------------------------
// R12 layout (strides 136/200, b64 fragment reads — conflict-free, 194 µs)
// + R13 VALU diet (bias as MFMA C-operand, packed-f32 epilogues — verified
// -8 µs VALU-busy). 128 edges = 8 i x 16 j, 256 threads (4 waves), 5 LDS
// barriers.
// Wide layers (L1,L2): waves split 192 out-ch (chunks {w, w+4, w+8}), 8 tiles.
// Narrow layers (L3,L4): wave pairs split 96 out-ch, 4 tiles each; L5
// partials via red[] after barrier 5.
// K=128-scaled fp8 MFMA (scale=1.0): L1 1 scaled; L2/L3 1 scaled + 2 reg
// (K=192); L4 1 scaled (K=96 zero-padded; w4 pre-padded).
// LDS 52224 B -> 3 blocks/CU; __launch_bounds__(256,3) = ~170-reg cap
// (R6 lesson: tight caps spill catastrophically).
__global__ __launch_bounds__(256, 3) void mlp_edges(
    const __bf16* __restrict__ xb,
    const unsigned char* __restrict__ w1p, const float* __restrict__ b1,
    const unsigned char* __restrict__ w2p, const float* __restrict__ b2,
    const unsigned char* __restrict__ w3p, const float* __restrict__ b3,
    const unsigned char* __restrict__ w4p, const float* __restrict__ b4,
    const float* __restrict__ w5,  const float* __restrict__ b5,
    float* __restrict__ out)
{
    __shared__ __align__(16) unsigned char AbufB[128 * 200];
    __shared__ __align__(16) unsigned char BbufB[128 * 200];
    __shared__ float red[256];

    const int t = threadIdx.x;
    const int lane = t & 63, wave = t >> 6;
    const int l15 = lane & 15, q = lane >> 4, q8 = q * 8, q32 = q * 32;
    const int j0 = blockIdx.x * 16, i0 = blockIdx.y * 8, b = blockIdx.z;

    // ---- JIT w1 (wide split) + b1 ----
    i32x8 w1v[3]; f32x4 b1v[3];
#pragma unroll
    for (int u = 0; u < 3; ++u) {
        const int ch = (wave + u * 4) * 16;
        b1v[u] = *(const f32x4*)(b1 + ch + q * 4);
        w1v[u] = *(const i32x8*)(w1p + (size_t)(ch + l15) * 128 + q32);
    }
    __builtin_amdgcn_sched_barrier(0);   // keep loads above the barrier

    // ---- stage d = |x_i - x_j| as fp8, 128 rows, stride 136 ----
    {
        const int m = t >> 1, c0 = (t & 1) * 64;   // 2 threads/row, 64 ch each
        const __bf16* xi = xb + ((size_t)b * NN + (i0 + (m >> 4))) * CC + c0;
        const __bf16* xj = xb + ((size_t)b * NN + (j0 + (m & 15))) * CC + c0;
        unsigned char* drow = AbufB + m * 136 + c0;
#pragma unroll
        for (int h = 0; h < 4; ++h) {              // 4 groups of 16 channels
            bf16x8 a0  = *(const bf16x8*)(xi + h * 16);
            bf16x8 a1  = *(const bf16x8*)(xi + h * 16 + 8);
            bf16x8 c0v = *(const bf16x8*)(xj + h * 16);
            bf16x8 c1v = *(const bf16x8*)(xj + h * 16 + 8);
            float dv[16];
#pragma unroll
            for (int u = 0; u < 8; ++u) {
                dv[u]     = fabsf((float)a0[u] - (float)c0v[u]);
                dv[u + 8] = fabsf((float)a1[u] - (float)c1v[u]);
            }
            int2 lo = make_int2(pk4(dv[0], dv[1], dv[2],  dv[3]),
                                pk4(dv[4], dv[5], dv[6],  dv[7]));
            int2 hi = make_int2(pk4(dv[8], dv[9], dv[10], dv[11]),
                                pk4(dv[12], dv[13], dv[14], dv[15]));
            *(int2*)(drow + h * 16)     = lo;
            *(int2*)(drow + h * 16 + 8) = hi;
        }
    }

    barrier_lds();                                        // barrier 1

    // ---- L1 (wide): d(136) -> h1(200); 1 scaled MFMA per acc, 8 tiles ----
#pragma unroll
    for (int nt = 0; nt < 8; ++nt) {
        i32x8 bfs = ld_lds32(AbufB + (nt * 16 + l15) * 136 + q32);
        unsigned char* orow = BbufB + (nt * 16 + l15) * 200 + q * 4;
#pragma unroll
        for (int u = 0; u < 3; ++u) {
            f32x4 acc = __builtin_amdgcn_mfma_scale_f32_16x16x128_f8f6f4(
                            w1v[u], bfs, b1v[u], 0, 0, 0, SCL, 0, SCL);
            *(int*)(orow + (wave + u * 4) * 16) = pk_lrelu(acc);
        }
    }

    // ---- JIT w2 (wide, K=192: scaled 128 + 2x32) + b2 ----
    i32x8 w2s[3]; long long w2r[3][2]; f32x4 b2v[3];
#pragma unroll
    for (int u = 0; u < 3; ++u) {
        const int ch = (wave + u * 4) * 16;
        b2v[u] = *(const f32x4*)(b2 + ch + q * 4);
        const unsigned char* wrow = w2p + (size_t)(ch + l15) * 192;
        w2s[u] = *(const i32x8*)(wrow + q32);
        w2r[u][0] = *(const long long*)(wrow + 128 + q8);
        w2r[u][1] = *(const long long*)(wrow + 160 + q8);
    }
    __builtin_amdgcn_sched_barrier(0);

    barrier_lds();                                        // barrier 2

    // ---- L2 (wide): h1(200) -> h2(200), 8 tiles ----
#pragma unroll
    for (int nt = 0; nt < 8; ++nt) {
        const unsigned char* inrow = BbufB + (nt * 16 + l15) * 200;
        i32x8 bfs = ld_lds32(inrow + q32);
        long long bfr0 = *(const long long*)(inrow + 128 + q8);
        long long bfr1 = *(const long long*)(inrow + 160 + q8);
        unsigned char* orow = AbufB + (nt * 16 + l15) * 200 + q * 4;
#pragma unroll
        for (int u = 0; u < 3; ++u) {
            f32x4 acc = __builtin_amdgcn_mfma_scale_f32_16x16x128_f8f6f4(
                            w2s[u], bfs, b2v[u], 0, 0, 0, SCL, 0, SCL);
            acc = __builtin_amdgcn_mfma_f32_16x16x32_fp8_fp8(w2r[u][0], bfr0, acc, 0, 0, 0);
            acc = __builtin_amdgcn_mfma_f32_16x16x32_fp8_fp8(w2r[u][1], bfr1, acc, 0, 0, 0);
            *(int*)(orow + (wave + u * 4) * 16) = pk_lrelu(acc);
        }
    }

    // ---- JIT w3 (narrow split) + b3 ----
    const int mc0n = (wave & 1) * 3;      // narrow: ch chunks
    const int nlo  = (wave >> 1) * 4;     // narrow: 4 edge tiles per wave
    i32x8 w3s[3]; long long w3r[3][2]; f32x4 b3v[3];
#pragma unroll
    for (int u = 0; u < 3; ++u) {
        const int ch = (mc0n + u) * 16;
        b3v[u] = *(const f32x4*)(b3 + ch + q * 4);
        const unsigned char* wrow = w3p + (size_t)(ch + l15) * 192;
        w3s[u] = *(const i32x8*)(wrow + q32);
        w3r[u][0] = *(const long long*)(wrow + 128 + q8);
        w3r[u][1] = *(const long long*)(wrow + 160 + q8);
    }
    __builtin_amdgcn_sched_barrier(0);

    barrier_lds();                                        // barrier 3

    // zero-pad h3 cols 96..127 (stride-136 rows in Bbuf; h1 is dead now)
    {
        unsigned char* pz = BbufB + (t >> 1) * 136 + 96 + (t & 1) * 16;
        *(long long*)(pz)     = 0;
        *(long long*)(pz + 8) = 0;
    }

    // ---- L3: h2(200) -> h3(136, K-padded), 4 tiles per wave ----
#pragma unroll
    for (int ntl = 0; ntl < 4; ++ntl) {
        const int nt = nlo + ntl;
        const unsigned char* inrow = AbufB + (nt * 16 + l15) * 200;
        i32x8 bfs = ld_lds32(inrow + q32);
        long long bfr0 = *(const long long*)(inrow + 128 + q8);
        long long bfr1 = *(const long long*)(inrow + 160 + q8);
        unsigned char* orow = BbufB + (nt * 16 + l15) * 136 + q * 4;
#pragma unroll
        for (int u = 0; u < 3; ++u) {
            f32x4 acc = __builtin_amdgcn_mfma_scale_f32_16x16x128_f8f6f4(
                            w3s[u], bfs, b3v[u], 0, 0, 0, SCL, 0, SCL);
            acc = __builtin_amdgcn_mfma_f32_16x16x32_fp8_fp8(w3r[u][0], bfr0, acc, 0, 0, 0);
            acc = __builtin_amdgcn_mfma_f32_16x16x32_fp8_fp8(w3r[u][1], bfr1, acc, 0, 0, 0);
            *(int*)(orow + (mc0n + u) * 16) = pk_lrelu(acc);
        }
    }

    // ---- JIT w4 (padded K=128 scaled) + b4 + w5 ----
    i32x8 w4s[3]; f32x4 b4v[3], w5v[3];
#pragma unroll
    for (int u = 0; u < 3; ++u) {
        const int ch = (mc0n + u) * 16;
        b4v[u] = *(const f32x4*)(b4 + ch + q * 4);
        w5v[u] = *(const f32x4*)(w5 + ch + q * 4);
        w4s[u] = *(const i32x8*)(w4p + (size_t)(ch + l15) * 128 + q32);
    }
    __builtin_amdgcn_sched_barrier(0);

    barrier_lds();                                        // barrier 4

    // ---- L4 (1 scaled MFMA per acc) + L5 dot -> logit partials, 4 tiles ----
#pragma unroll
    for (int ntl = 0; ntl < 4; ++ntl) {
        const int nt = nlo + ntl;
        i32x8 bfs = ld_lds32(BbufB + (nt * 16 + l15) * 136 + q32);
        f32x2 p2 = {0.f, 0.f};
#pragma unroll
        for (int u = 0; u < 3; ++u) {
            f32x4 acc = __builtin_amdgcn_mfma_scale_f32_16x16x128_f8f6f4(
                            w4s[u], bfs, b4v[u], 0, 0, 0, SCL, 0, SCL);
            f32x2 lo = {acc[0], acc[1]}, hi = {acc[2], acc[3]};
            lo = __builtin_elementwise_max(lo, lo * 0.01f);
            hi = __builtin_elementwise_max(hi, hi * 0.01f);
            f32x2 w5lo = {w5v[u][0], w5v[u][1]}, w5hi = {w5v[u][2], w5v[u][3]};
            p2 += lo * w5lo + hi * w5hi;   // v_pk_fma_f32
        }
        float p = p2[0] + p2[1];
        p += __shfl_xor(p, 16, 64);   // combine quads (k-parts of w5 dot)
        p += __shfl_xor(p, 32, 64);
        if (q == 0) red[(wave * 4 + ntl) * 16 + l15] = p;
    }

    barrier_lds();                                        // barrier 5

    if (t < 128) {   // combine wave-pair partials: 128 logits
        const int tile = t >> 4, e = t & 15;
        const int pair = tile >> 2, tl = tile & 3;
        const float logit = red[((pair * 2 + 0) * 4 + tl) * 16 + e]
                          + red[((pair * 2 + 1) * 4 + tl) * 16 + e] + b5[0];
        const int i = i0 + tile;
        const int j = j0 + e;
        out[(((size_t)b * NN + i) * NN + j) * 2 + 1] = logit;
    }
}

// ---------------- softmax over j per (b,i) row, in place on out -------------
__global__ __launch_bounds__(256) void softmax_rows(float* __restrict__ out)
{
    const int row = blockIdx.x;           // b*512 + i
    const int i   = row & (NN - 1);
    float* base = out + (size_t)row * (NN * 2);
    const int t = threadIdx.x;

    float v0 = base[t * 2 + 1];
    float v1 = base[(t + 256) * 2 + 1];
    if (t == i)       v0 = -__builtin_inff();   // self-edge mask
    if (t + 256 == i) v1 = -__builtin_inff();

    float mx = fmaxf(v0, v1);
#pragma unroll
    for (int off = 32; off; off >>= 1) mx = fmaxf(mx, __shfl_xor(mx, off, 64));
    __shared__ float sm[4], ss[4];
    const int wave = t >> 6, lane = t & 63;
    if (lane == 0) sm[wave] = mx;
    __syncthreads();
    mx = fmaxf(fmaxf(sm[0], sm[1]), fmaxf(sm[2], sm[3]));

    const float e0 = __expf(v0 - mx), e1 = __expf(v1 - mx);
    float s = e0 + e1;
#pragma unroll
    for (int off = 32; off; off >>= 1) s += __shfl_xor(s, off, 64);
    if (lane == 0) ss[wave] = s;
    __syncthreads();
    s = ss[0] + ss[1] + ss[2] + ss[3];
    const float inv = 1.0f / s;

    float2* o2 = (float2*)base;
    o2[t]       = make_float2(t == i ? 1.f : 0.f,         e0 * inv);
    o2[t + 256] = make_float2((t + 256) == i ? 1.f : 0.f, e1 * inv);
}

// ---------------- host launch ----------------
extern "C" void kernel_launch(void* const* d_in, const int* in_sizes, int n_in,
                              void* d_out, int out_size, void* d_ws, size_t ws_size,
                              hipStream_t stream) {
    const float* x  = (const float*)d_in[0];
    // d_in[1] = W_id (pure eye broadcast; synthesized in-kernel)
    const float* w1 = (const float*)d_in[2];
    const float* b1 = (const float*)d_in[3];
    const float* w2 = (const float*)d_in[4];
    const float* b2 = (const float*)d_in[5];
    const float* w3 = (const float*)d_in[6];
    const float* b3 = (const float*)d_in[7];
    const float* w4 = (const float*)d_in[8];
    const float* b4 = (const float*)d_in[9];
    const float* w5 = (const float*)d_in[10];
    const float* b5 = (const float*)d_in[11];
    float* out = (float*)d_out;

    // ws: xb 524288 | w1f 24576 | w2f 36864 | w3f 18432 | w4fp 12288
    char* ws = (char*)d_ws;
    __bf16*        xb   = (__bf16*)(ws);
    unsigned char* w1f  = (unsigned char*)(ws + 524288);
    unsigned char* w2f  = (unsigned char*)(ws + 548864);
    unsigned char* w3f  = (unsigned char*)(ws + 585728);
    unsigned char* w4fp = (unsigned char*)(ws + 604160);

    cvt_all<<<(88000 + 255) / 256, 256, 0, stream>>>(x, xb, w1, (int*)w1f,
                                                     w2, (int*)w2f, w3, (int*)w3f,
                                                     w4, w4fp);

    dim3 grid(NN / 16, NN / 8, NB);   // j-tiles, i-tiles (8 rows), batch
    mlp_edges<<<grid, 256, 0, stream>>>(xb, w1f, b1, w2f, b2, w3f, b3, w4fp, b4,
                                        w5, b5, out);

    softmax_rows<<<NB * NN, 256, 0, stream>>>(out);
}

// Round 15
// 248.057 us; speedup vs baseline: 1.0232x; 1.0232x over previous
//
#include <hip/hip_runtime.h>
#include <hip/hip_bf16.h>

// Problem constants (B,N,C,NF) = (4,512,128,96)
#define NB 4
#define NN 512
#define CC 128

typedef __bf16 bf16x8 __attribute__((ext_vector_type(8)));
typedef __bf16 bf16x4 __attribute__((ext_vector_type(4)));
typedef float  f32x4  __attribute__((ext_vector_type(4)));
typedef int    i32x8  __attribute__((ext_vector_type(8)));

#define SCL 0x7F7F7F7F   // E8M0 127 (=1.0) in every byte — scale-neutral

// LDS-only barrier: drains lgkmcnt; global loads may stay in flight.
__device__ __forceinline__ void barrier_lds() {
    __builtin_amdgcn_s_waitcnt(0xC07F);
    __builtin_amdgcn_fence(__ATOMIC_RELEASE, "workgroup", "local");
    __builtin_amdgcn_s_barrier();
    __builtin_amdgcn_fence(__ATOMIC_ACQUIRE, "workgroup", "local");
}

__device__ __forceinline__ float lrelu(float v) { return fmaxf(v, 0.01f * v); }

__device__ __forceinline__ int pk4(float a, float b, float c, float d) {
    int p = __builtin_amdgcn_cvt_pk_fp8_f32(a, b, 0, false);
    return  __builtin_amdgcn_cvt_pk_fp8_f32(c, d, p, true);
}

// load 32 fp8 (8 dwords) from LDS via 4x b64 — R12/R13 A/B: b64 at row
// stride ≡2 mod 32 dwords is conflict-free; b128 at stride ≡4 takes 4-way
// conflicts (SQ_LDS_BANK_CONFLICT 2.6e5 vs 1.36e7). Keep b64 + 136/200.
__device__ __forceinline__ i32x8 ld_lds32(const unsigned char* p) {
    i32x8 r;
    long long* q = (long long*)&r;
    q[0] = *(const long long*)(p);
    q[1] = *(const long long*)(p + 8);
    q[2] = *(const long long*)(p + 16);
    q[3] = *(const long long*)(p + 24);
    return r;
}

// ---------- prepass: x -> bf16; w1..w3 -> fp8; w4 -> fp8 zero-padded K=128 ----
__global__ void cvt_all(const float* __restrict__ x,  __bf16* __restrict__ xb,
                        const float* __restrict__ w1, int* __restrict__ w1f,
                        const float* __restrict__ w2, int* __restrict__ w2f,
                        const float* __restrict__ w3, int* __restrict__ w3f,
                        const float* __restrict__ w4, unsigned char* __restrict__ w4fp)
{
    int idx = blockIdx.x * blockDim.x + threadIdx.x;
    if (idx < 65536) {                       // x: 262144 f32 -> bf16
        float4 v = ((const float4*)x)[idx];
        bf16x4 o = { (__bf16)v.x, (__bf16)v.y, (__bf16)v.z, (__bf16)v.w };
        ((bf16x4*)xb)[idx] = o;
    } else if (idx < 85504) {                // w1..w3 -> fp8, packed rows
        const float* s; int* d; int off;
        if      (idx < 71680) { s = w1; d = w1f; off = idx - 65536; }  // 24576 f32
        else if (idx < 80896) { s = w2; d = w2f; off = idx - 71680; }  // 36864
        else                  { s = w3; d = w3f; off = idx - 80896; }  // 18432
        float4 v = ((const float4*)s)[off];
        d[off] = pk4(v.x, v.y, v.z, v.w);
    } else if (idx < 87808) {                // w4 -> fp8 into 128-wide rows
        int off = idx - 85504;               // 2304 float4s = 96 rows x 24
        int r = off / 24, c = (off % 24) * 4;
        float4 v = ((const float4*)w4)[off];
        *(int*)(w4fp + r * 128 + c) = pk4(v.x, v.y, v.z, v.w);
    } else if (idx < 88000) {                // zero-pad w4 rows, cols 96..127
        int p = idx - 87808;                 // 192 int4s
        int r = p >> 1;
        *(int4*)(w4fp + r * 128 + 96 + (p & 1) * 16) = make_int4(0, 0, 0, 0);
    }
}

// ---------------- fused edge-MLP kernel -------------------------------------
// R12 configuration — measured best (194 µs kernel / 250.2 µs total).
// 128 edges = 8 i x 16 j, 256 threads (4 waves), 5 LDS barriers.
// Wide layers (L1,L2): waves split 192 out-ch (chunks {w, w+4, w+8}), 8 tiles.
// Narrow layers (L3,L4): wave pairs split 96 out-ch, 4 tiles each; L5
// partials via red[] after barrier 5.
// K=128-scaled fp8 MFMA (scale=1.0): L1 1 scaled; L2/L3 1 scaled + 2 reg
// (K=192); L4 1 scaled (K=96 zero-padded; w4 pre-padded).
// Strides 136/200 (both ≡2 mod 32 dwords) + b64 fragment reads: conflict-free
// (R13's 16B-aligned 144/208 + b128 took 4-way conflicts, 52x counter jump).
// Plain scalar lrelu + explicit acc-init: R13/R14 measured the "VALU diet"
// (bias as C-operand, packed-f32 epilogue) as neutral-to-negative — marginal
// VALU is NOT on the critical path; don't re-apply it.
// JIT weight loads hoisted above each barrier (sched_barrier) so barrier
// wait covers their latency (R5/R9: tail-exposed loads regress badly).
// LDS 52224 B -> 3 blocks/CU (structural: h1/h2 rows >=192 B);
// __launch_bounds__(256,3) = ~170-reg cap (R6: tight caps spill 408 MB).
__global__ __launch_bounds__(256, 3) void mlp_edges(
    const __bf16* __restrict__ xb,
    const unsigned char* __restrict__ w1p, const float* __restrict__ b1,
    const unsigned char* __restrict__ w2p, const float* __restrict__ b2,
    const unsigned char* __restrict__ w3p, const float* __restrict__ b3,
    const unsigned char* __restrict__ w4p, const float* __restrict__ b4,
    const float* __restrict__ w5,  const float* __restrict__ b5,
    float* __restrict__ out)
{
    __shared__ __align__(16) unsigned char AbufB[128 * 200];
    __shared__ __align__(16) unsigned char BbufB[128 * 200];
    __shared__ float red[256];

    const int t = threadIdx.x;
    const int lane = t & 63, wave = t >> 6;
    const int l15 = lane & 15, q = lane >> 4, q8 = q * 8, q32 = q * 32;
    const int j0 = blockIdx.x * 16, i0 = blockIdx.y * 8, b = blockIdx.z;

    // ---- JIT w1 (wide split) + b1 ----
    i32x8 w1v[3]; f32x4 b1v[3];
#pragma unroll
    for (int u = 0; u < 3; ++u) {
        const int ch = (wave + u * 4) * 16;
        b1v[u] = *(const f32x4*)(b1 + ch + q * 4);
        w1v[u] = *(const i32x8*)(w1p + (size_t)(ch + l15) * 128 + q32);
    }
    __builtin_amdgcn_sched_barrier(0);   // keep loads above the barrier

    // ---- stage d = |x_i - x_j| as fp8, 128 rows, stride 136 ----
    {
        const int m = t >> 1, c0 = (t & 1) * 64;   // 2 threads/row, 64 ch each
        const __bf16* xi = xb + ((size_t)b * NN + (i0 + (m >> 4))) * CC + c0;
        const __bf16* xj = xb + ((size_t)b * NN + (j0 + (m & 15))) * CC + c0;
        unsigned char* drow = AbufB + m * 136 + c0;
#pragma unroll
        for (int h = 0; h < 4; ++h) {              // 4 groups of 16 channels
            bf16x8 a0  = *(const bf16x8*)(xi + h * 16);
            bf16x8 a1  = *(const bf16x8*)(xi + h * 16 + 8);
            bf16x8 c0v = *(const bf16x8*)(xj + h * 16);
            bf16x8 c1v = *(const bf16x8*)(xj + h * 16 + 8);
            float dv[16];
#pragma unroll
            for (int u = 0; u < 8; ++u) {
                dv[u]     = fabsf((float)a0[u] - (float)c0v[u]);
                dv[u + 8] = fabsf((float)a1[u] - (float)c1v[u]);
            }
            int2 lo = make_int2(pk4(dv[0], dv[1], dv[2],  dv[3]),
                                pk4(dv[4], dv[5], dv[6],  dv[7]));
            int2 hi = make_int2(pk4(dv[8], dv[9], dv[10], dv[11]),
                                pk4(dv[12], dv[13], dv[14], dv[15]));
            *(int2*)(drow + h * 16)     = lo;
            *(int2*)(drow + h * 16 + 8) = hi;
        }
    }

    barrier_lds();                                        // barrier 1

    // ---- L1 (wide): d(136) -> h1(200); 1 scaled MFMA per acc, 8 tiles ----
#pragma unroll
    for (int nt = 0; nt < 8; ++nt) {
        i32x8 bfs = ld_lds32(AbufB + (nt * 16 + l15) * 136 + q32);
        f32x4 acc[3] = { b1v[0], b1v[1], b1v[2] };
#pragma unroll
        for (int u = 0; u < 3; ++u)
            acc[u] = __builtin_amdgcn_mfma_scale_f32_16x16x128_f8f6f4(
                         w1v[u], bfs, acc[u], 0, 0, 0, SCL, 0, SCL);
        unsigned char* orow = BbufB + (nt * 16 + l15) * 200 + q * 4;
#pragma unroll
        for (int u = 0; u < 3; ++u)
            *(int*)(orow + (wave + u * 4) * 16) =
                pk4(lrelu(acc[u][0]), lrelu(acc[u][1]), lrelu(acc[u][2]), lrelu(acc[u][3]));
    }

    // ---- JIT w2 (wide, K=192: scaled 128 + 2x32) + b2 ----
    i32x8 w2s[3]; long long w2r[3][2]; f32x4 b2v[3];
#pragma unroll
    for (int u = 0; u < 3; ++u) {
        const int ch = (wave + u * 4) * 16;
        b2v[u] = *(const f32x4*)(b2 + ch + q * 4);
        const unsigned char* wrow = w2p + (size_t)(ch + l15) * 192;
        w2s[u] = *(const i32x8*)(wrow + q32);
        w2r[u][0] = *(const long long*)(wrow + 128 + q8);
        w2r[u][1] = *(const long long*)(wrow + 160 + q8);
    }
    __builtin_amdgcn_sched_barrier(0);

    barrier_lds();                                        // barrier 2

    // ---- L2 (wide): h1(200) -> h2(200), 8 tiles ----
#pragma unroll
    for (int nt = 0; nt < 8; ++nt) {
        const unsigned char* inrow = BbufB + (nt * 16 + l15) * 200;
        i32x8 bfs = ld_lds32(inrow + q32);
        long long bfr0 = *(const long long*)(inrow + 128 + q8);
        long long bfr1 = *(const long long*)(inrow + 160 + q8);
        f32x4 acc[3] = { b2v[0], b2v[1], b2v[2] };
#pragma unroll
        for (int u = 0; u < 3; ++u) {
            acc[u] = __builtin_amdgcn_mfma_scale_f32_16x16x128_f8f6f4(
                         w2s[u], bfs, acc[u], 0, 0, 0, SCL, 0, SCL);
            acc[u] = __builtin_amdgcn_mfma_f32_16x16x32_fp8_fp8(w2r[u][0], bfr0, acc[u], 0, 0, 0);
            acc[u] = __builtin_amdgcn_mfma_f32_16x16x32_fp8_fp8(w2r[u][1], bfr1, acc[u], 0, 0, 0);
        }
        unsigned char* orow = AbufB + (nt * 16 + l15) * 200 + q * 4;
#pragma unroll
        for (int u = 0; u < 3; ++u)
            *(int*)(orow + (wave + u * 4) * 16) =
                pk4(lrelu(acc[u][0]), lrelu(acc[u][1]), lrelu(acc[u][2]), lrelu(acc[u][3]));
    }

    // ---- JIT w3 (narrow split) + b3 ----
    const int mc0n = (wave & 1) * 3;      // narrow: ch chunks
    const int nlo  = (wave >> 1) * 4;     // narrow: 4 edge tiles per wave
    i32x8 w3s[3]; long long w3r[3][2]; f32x4 b3v[3];
#pragma unroll
    for (int u = 0; u < 3; ++u) {
        const int ch = (mc0n + u) * 16;
        b3v[u] = *(const f32x4*)(b3 + ch + q * 4);
        const unsigned char* wrow = w3p + (size_t)(ch + l15) * 192;
        w3s[u] = *(const i32x8*)(wrow + q32);
        w3r[u][0] = *(const long long*)(wrow + 128 + q8);
        w3r[u][1] = *(const long long*)(wrow + 160 + q8);
    }
    __builtin_amdgcn_sched_barrier(0);

    barrier_lds();                                        // barrier 3

    // zero-pad h3 cols 96..127 (stride-136 rows in Bbuf; h1 is dead now)
    {
        unsigned char* pz = BbufB + (t >> 1) * 136 + 96 + (t & 1) * 16;
        *(long long*)(pz)     = 0;
        *(long long*)(pz + 8) = 0;
    }

    // ---- L3: h2(200) -> h3(136, K-padded), 4 tiles per wave ----
#pragma unroll
    for (int ntl = 0; ntl < 4; ++ntl) {
        const int nt = nlo + ntl;
        const unsigned char* inrow = AbufB + (nt * 16 + l15) * 200;
        i32x8 bfs = ld_lds32(inrow + q32);
        long long bfr0 = *(const long long*)(inrow + 128 + q8);
        long long bfr1 = *(const long long*)(inrow + 160 + q8);
        f32x4 acc[3] = { b3v[0], b3v[1], b3v[2] };
#pragma unroll
        for (int u = 0; u < 3; ++u) {
            acc[u] = __builtin_amdgcn_mfma_scale_f32_16x16x128_f8f6f4(
                         w3s[u], bfs, acc[u], 0, 0, 0, SCL, 0, SCL);
            acc[u] = __builtin_amdgcn_mfma_f32_16x16x32_fp8_fp8(w3r[u][0], bfr0, acc[u], 0, 0, 0);
            acc[u] = __builtin_amdgcn_mfma_f32_16x16x32_fp8_fp8(w3r[u][1], bfr1, acc[u], 0, 0, 0);
        }
        unsigned char* orow = BbufB + (nt * 16 + l15) * 136 + q * 4;
#pragma unroll
        for (int u = 0; u < 3; ++u)
            *(int*)(orow + (mc0n + u) * 16) =
                pk4(lrelu(acc[u][0]), lrelu(acc[u][1]), lrelu(acc[u][2]), lrelu(acc[u][3]));
    }

    // ---- JIT w4 (padded K=128 scaled) + b4 + w5 ----
    i32x8 w4s[3]; f32x4 b4v[3], w5v[3];
#pragma unroll
    for (int u = 0; u < 3; ++u) {
        const int ch = (mc0n + u) * 16;
        b4v[u] = *(const f32x4*)(b4 + ch + q * 4);
        w5v[u] = *(const f32x4*)(w5 + ch + q * 4);
        w4s[u] = *(const i32x8*)(w4p + (size_t)(ch + l15) * 128 + q32);
    }
    __builtin_amdgcn_sched_barrier(0);

    barrier_lds();                                        // barrier 4

    // ---- L4 (1 scaled MFMA per acc) + L5 dot -> logit partials, 4 tiles ----
#pragma unroll
    for (int ntl = 0; ntl < 4; ++ntl) {
        const int nt = nlo + ntl;
        i32x8 bfs = ld_lds32(BbufB + (nt * 16 + l15) * 136 + q32);
        f32x4 acc[3] = { b4v[0], b4v[1], b4v[2] };
#pragma unroll
        for (int u = 0; u < 3; ++u)
            acc[u] = __builtin_amdgcn_mfma_scale_f32_16x16x128_f8f6f4(
                         w4s[u], bfs, acc[u], 0, 0, 0, SCL, 0, SCL);
        float p = 0.f;
#pragma unroll
        for (int u = 0; u < 3; ++u)
#pragma unroll
            for (int r = 0; r < 4; ++r)
                p += lrelu(acc[u][r]) * w5v[u][r];
        p += __shfl_xor(p, 16, 64);   // combine quads (k-parts of w5 dot)
        p += __shfl_xor(p, 32, 64);
        if (q == 0) red[(wave * 4 + ntl) * 16 + l15] = p;
    }

    barrier_lds();                                        // barrier 5

    if (t < 128) {   // combine wave-pair partials: 128 logits
        const int tile = t >> 4, e = t & 15;
        const int pair = tile >> 2, tl = tile & 3;
        const float logit = red[((pair * 2 + 0) * 4 + tl) * 16 + e]
                          + red[((pair * 2 + 1) * 4 + tl) * 16 + e] + b5[0];
        const int i = i0 + tile;
        const int j = j0 + e;
        out[(((size_t)b * NN + i) * NN + j) * 2 + 1] = logit;
    }
}

// ---------------- softmax over j per (b,i) row, in place on out -------------
__global__ __launch_bounds__(256) void softmax_rows(float* __restrict__ out)
{
    const int row = blockIdx.x;           // b*512 + i
    const int i   = row & (NN - 1);
    float* base = out + (size_t)row * (NN * 2);
    const int t = threadIdx.x;

    float v0 = base[t * 2 + 1];
    float v1 = base[(t + 256) * 2 + 1];
    if (t == i)       v0 = -__builtin_inff();   // self-edge mask
    if (t + 256 == i) v1 = -__builtin_inff();

    float mx = fmaxf(v0, v1);
#pragma unroll
    for (int off = 32; off; off >>= 1) mx = fmaxf(mx, __shfl_xor(mx, off, 64));
    __shared__ float sm[4], ss[4];
    const int wave = t >> 6, lane = t & 63;
    if (lane == 0) sm[wave] = mx;
    __syncthreads();
    mx = fmaxf(fmaxf(sm[0], sm[1]), fmaxf(sm[2], sm[3]));

    const float e0 = __expf(v0 - mx), e1 = __expf(v1 - mx);
    float s = e0 + e1;
#pragma unroll
    for (int off = 32; off; off >>= 1) s += __shfl_xor(s, off, 64);
    if (lane == 0) ss[wave] = s;
    __syncthreads();
    s = ss[0] + ss[1] + ss[2] + ss[3];
    const float inv = 1.0f / s;

    float2* o2 = (float2*)base;
    o2[t]       = make_float2(t == i ? 1.f : 0.f,         e0 * inv);
    o2[t + 256] = make_float2((t + 256) == i ? 1.f : 0.f, e1 * inv);
}

// ---------------- host launch ----------------
extern "C" void kernel_launch(void* const* d_in, const int* in_sizes, int n_in,
                              void* d_out, int out_size, void* d_ws, size_t ws_size,
                              hipStream_t stream) {
    const float* x  = (const float*)d_in[0];
    // d_in[1] = W_id (pure eye broadcast; synthesized in-kernel)
    const float* w1 = (const float*)d_in[2];
    const float* b1 = (const float*)d_in[3];
    const float* w2 = (const float*)d_in[4];
    const float* b2 = (const float*)d_in[5];
    const float* w3 = (const float*)d_in[6];
    const float* b3 = (const float*)d_in[7];
    const float* w4 = (const float*)d_in[8];
    const float* b4 = (const float*)d_in[9];
    const float* w5 = (const float*)d_in[10];
    const float* b5 = (const float*)d_in[11];
    float* out = (float*)d_out;

    // ws: xb 524288 | w1f 24576 | w2f 36864 | w3f 18432 | w4fp 12288
    char* ws = (char*)d_ws;
    __bf16*        xb   = (__bf16*)(ws);
    unsigned char* w1f  = (unsigned char*)(ws + 524288);
    unsigned char* w2f  = (unsigned char*)(ws + 548864);
    unsigned char* w3f  = (unsigned char*)(ws + 585728);
    unsigned char* w4fp = (unsigned char*)(ws + 604160);

    cvt_all<<<(88000 + 255) / 256, 256, 0, stream>>>(x, xb, w1, (int*)w1f,
                                                     w2, (int*)w2f, w3, (int*)w3f,
                                                     w4, w4fp);

    dim3 grid(NN / 16, NN / 8, NB);   // j-tiles, i-tiles (8 rows), batch
    mlp_edges<<<grid, 256, 0, stream>>>(xb, w1f, b1, w2f, b2, w3f, b3, w4fp, b4,
                                        w5, b5, out);

    softmax_rows<<<NB * NN, 256, 0, stream>>>(out);
}